// Round 1
// 1067.284 us; speedup vs baseline: 1.8431x; 1.8431x over previous
//
#include <hip/hip_runtime.h>
#include <hip/hip_bf16.h>
#include <math.h>

#define B_ 8
#define C_ 256
#define H_ 64
#define W_ 64
#define N_ 4096
#define M_ 1024
#define HW_ 4096

typedef __attribute__((ext_vector_type(8))) short short8;
typedef __attribute__((ext_vector_type(4))) float f32x4;

__device__ __forceinline__ unsigned short f2bf(float x) {
    unsigned u = __float_as_uint(x);
    u += 0x7fffu + ((u >> 16) & 1u);          // round-to-nearest-even
    return (unsigned short)(u >> 16);
}
__device__ __forceinline__ float bf2f(unsigned short h) {
    return __uint_as_float(((unsigned)h) << 16);
}

// ---------------------------------------------------------------------------
// Split Wq [256co][256ci][3][3] fp32 -> per-tap bf16 hi/lo [9][256co][256ci].
__global__ __launch_bounds__(256) void split_w_tap(
    const float* __restrict__ Wq, unsigned short* __restrict__ wtH,
    unsigned short* __restrict__ wtL)
{
    int co = blockIdx.x, ci = threadIdx.x;
    const float* wp = Wq + ((size_t)co * 256 + ci) * 9;
    #pragma unroll
    for (int tap = 0; tap < 9; ++tap) {
        float v = wp[tap];
        unsigned short h = f2bf(v), l = f2bf(v - bf2f(h));
        size_t o = ((size_t)tap << 16) + ((size_t)co << 8) + ci;
        wtH[o] = h; wtL[o] = l;
    }
}

// ---------------------------------------------------------------------------
// Transpose+split x [8][256][64][64] fp32 -> padded NHWC bf16 hi/lo
// [8][66][66][256] (halo pre-zeroed by memset). LDS-tiled transpose.
__global__ __launch_bounds__(256) void split_x_pad(
    const float* __restrict__ x, unsigned short* __restrict__ xpH,
    unsigned short* __restrict__ xpL)
{
    __shared__ float tile[64][65];
    int blk = blockIdx.x;            // b*64 + h
    int b = blk >> 6, h = blk & 63;
    int t = threadIdx.x;
    const float* xb = x + ((size_t)b << 20) + (size_t)h * 64;
    size_t obase = (((size_t)b * 4356) + (size_t)(h + 1) * 66 + 1) * 256;
    unsigned short* oH = xpH + obase;
    unsigned short* oL = xpL + obase;
    for (int cc = 0; cc < 256; cc += 64) {
        int wi = t & 63, cq = t >> 6;
        #pragma unroll
        for (int r = 0; r < 16; ++r) {
            int cl = cq * 16 + r;
            tile[cl][wi] = xb[((size_t)(cc + cl)) * 4096 + wi];
        }
        __syncthreads();
        int cl = t & 63, wq = t >> 6;
        #pragma unroll
        for (int r = 0; r < 16; ++r) {
            int wwi = wq * 16 + r;
            float v = tile[cl][wwi];
            unsigned short hh = f2bf(v), lo = f2bf(v - bf2f(hh));
            size_t o = (size_t)wwi * 256 + cc + cl;
            oH[o] = hh; oL[o] = lo;
        }
        __syncthreads();
    }
}

// ---------------------------------------------------------------------------
// conv 3x3 s1 p1 via MFMA: per-tap GEMM sum, split-bf16 3-term fp32 emulation.
// Grid 512 = 8 bat (XCD-pinned via blk&7) x 2 co-tiles x 32 px-tiles.
// Block 256 thr = 4 waves (2co x 2px), each wave 64co x 64px = 4x4 frags.
// Operands direct from global (L2-resident per XCD). Epilogue -> qH/qL pairs.
__global__ __launch_bounds__(256, 2) void conv3x3_mfma(
    const unsigned short* __restrict__ xpH, const unsigned short* __restrict__ xpL,
    const unsigned short* __restrict__ wtH, const unsigned short* __restrict__ wtL,
    const float* __restrict__ bq,
    unsigned short* __restrict__ qH, unsigned short* __restrict__ qL)
{
    int blk = blockIdx.x;
    int bat = blk & 7;
    int rest = blk >> 3;
    int cot = rest & 1;
    int pxt = rest >> 1;                  // 32 tiles of 128 px (2 rows of 64)
    int t = threadIdx.x;
    int wv = t >> 6;
    int wco = wv >> 1, wpx = wv & 1;
    int lane = t & 63;
    int ll = lane & 15, qd = lane >> 4;

    const int co0 = cot * 128 + wco * 64;
    // A-frag bases: lane ll = co_local, qd*8 = ci chunk
    const unsigned short* aHp[4]; const unsigned short* aLp[4];
    #pragma unroll
    for (int ib = 0; ib < 4; ++ib) {
        size_t o = ((size_t)(co0 + ib * 16 + ll)) * 256 + qd * 8;
        aHp[ib] = wtH + o; aLp[ib] = wtL + o;
    }
    // B-frag bases: lane ll = px_local, qd*8 = ci chunk, padded NHWC coords
    const unsigned short* bHp[4]; const unsigned short* bLp[4];
    const int h0 = pxt * 2;
    #pragma unroll
    for (int jb = 0; jb < 4; ++jb) {
        int pxl = wpx * 64 + jb * 16 + ll;
        int hh = h0 + (pxl >> 6);
        int ww = pxl & 63;
        size_t o = ((size_t)bat * 4356 + (size_t)hh * 66 + ww) * 256 + qd * 8;
        bHp[jb] = xpH + o; bLp[jb] = xpL + o;
    }

    f32x4 acc[4][4];
    #pragma unroll
    for (int i = 0; i < 4; ++i)
        #pragma unroll
        for (int j = 0; j < 4; ++j) acc[i][j] = (f32x4){0.f, 0.f, 0.f, 0.f};

    int boff = 0;   // (kh*66+kw)*256 shorts
    int kw = 0;
    for (int tap = 0; tap < 9; ++tap) {
        const int aoff = tap << 16;
        #pragma unroll 2
        for (int ci0 = 0; ci0 < 256; ci0 += 32) {
            short8 avh[4], avl[4], bvh[4], bvl[4];
            #pragma unroll
            for (int ib = 0; ib < 4; ++ib) {
                avh[ib] = *(const short8*)(aHp[ib] + aoff + ci0);
                avl[ib] = *(const short8*)(aLp[ib] + aoff + ci0);
            }
            #pragma unroll
            for (int jb = 0; jb < 4; ++jb) {
                bvh[jb] = *(const short8*)(bHp[jb] + boff + ci0);
                bvl[jb] = *(const short8*)(bLp[jb] + boff + ci0);
            }
            #pragma unroll
            for (int ib = 0; ib < 4; ++ib)
                #pragma unroll
                for (int jb = 0; jb < 4; ++jb) {
                    f32x4 o = acc[ib][jb];
                    o = __builtin_amdgcn_mfma_f32_16x16x32_bf16(avh[ib], bvh[jb], o, 0, 0, 0);
                    o = __builtin_amdgcn_mfma_f32_16x16x32_bf16(avl[ib], bvh[jb], o, 0, 0, 0);
                    o = __builtin_amdgcn_mfma_f32_16x16x32_bf16(avh[ib], bvl[jb], o, 0, 0, 0);
                    acc[ib][jb] = o;
                }
        }
        kw++;
        boff += 256;
        if (kw == 3) { kw = 0; boff += 63 * 256; }
    }

    // Epilogue: +bias, split to bf16 hi/lo, store to [B][C][4096].
    // D layout: row(co_local16) = qd*4+r, col(px_local16) = ll.
    const int pxbase = pxt * 128 + wpx * 64;
    #pragma unroll
    for (int ib = 0; ib < 4; ++ib) {
        #pragma unroll
        for (int r = 0; r < 4; ++r) {
            int co = co0 + ib * 16 + qd * 4 + r;
            float bvv = bq[co];
            size_t rowo = ((size_t)(bat * 256 + co)) << 12;
            #pragma unroll
            for (int jb = 0; jb < 4; ++jb) {
                float v = acc[ib][jb][r] + bvv;
                unsigned short h = f2bf(v), l = f2bf(v - bf2f(h));
                size_t o = rowo + pxbase + jb * 16 + ll;
                qH[o] = h; qL[o] = l;
            }
        }
    }
}

// ---------------------------------------------------------------------------
// conv 2x2, stride 2, pad 0 (k and v fused): pure GEMM, fp32 out (pre-GN).
__global__ __launch_bounds__(256) void conv2x2_kernel(
    const float* __restrict__ y,
    const float* __restrict__ Wk, const float* __restrict__ bk,
    const float* __restrict__ Wv, const float* __restrict__ bv,
    float* __restrict__ kout, float* __restrict__ vout)
{
    const int K = 1024;
    int blk = blockIdx.x;
    int cot = blk & 3;
    int mt  = (blk >> 2) & 7;
    int b   = blk >> 5;
    int t = threadIdx.x;
    int tx = t & 15, ty = t >> 4;
    const float* Wt; const float* bt; float* dst; int co0;
    if (cot < 2) { Wt = Wk; bt = bk; dst = kout; co0 = cot * 128; }
    else         { Wt = Wv; bt = bv; dst = vout; co0 = (cot - 2) * 128; }
    __shared__ float As[16][132];
    __shared__ float Bs[16][132];
    float acc[8][8] = {};
    const float* Wbase = Wt + (size_t)co0 * K;
    const float* yb = y + (size_t)b * C_ * HW_;
    const int m0 = mt * 128;
    const int a_kk = t & 15,  a_colb = t >> 4;
    const int b_px = t & 127, b_kkb  = t >> 7;

    for (int k0 = 0; k0 < K; k0 += 16) {
        #pragma unroll
        for (int r = 0; r < 8; ++r) {
            int col = r * 16 + a_colb;
            As[a_kk][col] = Wbase[(size_t)col * K + (k0 + a_kk)];
        }
        #pragma unroll
        for (int r = 0; r < 8; ++r) {
            int kk = 2 * r + b_kkb;
            int kg = k0 + kk;
            int ci = kg >> 2;
            int tap = kg & 3;
            int kh = tap >> 1;
            int kw = tap & 1;
            int m = m0 + b_px;
            int mh = m >> 5, mw = m & 31;
            Bs[kk][b_px] = yb[(size_t)ci * HW_ + (2 * mh + kh) * 64 + 2 * mw + kw];
        }
        __syncthreads();
        #pragma unroll
        for (int kk = 0; kk < 16; ++kk) {
            float a[8], bb[8];
            *(float4*)&a[0]  = *(const float4*)&As[kk][ty * 8];
            *(float4*)&a[4]  = *(const float4*)&As[kk][ty * 8 + 4];
            *(float4*)&bb[0] = *(const float4*)&Bs[kk][tx * 8];
            *(float4*)&bb[4] = *(const float4*)&Bs[kk][tx * 8 + 4];
            #pragma unroll
            for (int i = 0; i < 8; ++i)
                #pragma unroll
                for (int j = 0; j < 8; ++j)
                    acc[i][j] = fmaf(a[i], bb[j], acc[i][j]);
        }
        __syncthreads();
    }
    #pragma unroll
    for (int i = 0; i < 8; ++i) {
        int co = co0 + ty * 8 + i;
        float bv2 = bt[co];
        float* op = dst + ((size_t)(b * C_ + co)) * M_ + m0 + tx * 8;
        float4 o0 = make_float4(acc[i][0] + bv2, acc[i][1] + bv2, acc[i][2] + bv2, acc[i][3] + bv2);
        float4 o1 = make_float4(acc[i][4] + bv2, acc[i][5] + bv2, acc[i][6] + bv2, acc[i][7] + bv2);
        *(float4*)op = o0;
        *(float4*)(op + 4) = o1;
    }
}

// ---------------------------------------------------------------------------
// GroupNorm stats (fp32 input): one block per (batch, group).
__global__ __launch_bounds__(256) void gn_stats_kernel(
    const float* __restrict__ buf, float* __restrict__ stats, int S)
{
    int bg = blockIdx.x;
    const float4* p = (const float4*)(buf + (size_t)bg * 8 * S);
    int n4 = 2 * S;
    float s = 0.f, s2 = 0.f;
    for (int i = threadIdx.x; i < n4; i += 256) {
        float4 vv = p[i];
        s  += vv.x + vv.y + vv.z + vv.w;
        s2 += vv.x * vv.x + vv.y * vv.y + vv.z * vv.z + vv.w * vv.w;
    }
    for (int d = 1; d < 64; d <<= 1) { s += __shfl_xor(s, d); s2 += __shfl_xor(s2, d); }
    __shared__ float red[8];
    int w = threadIdx.x >> 6;
    if ((threadIdx.x & 63) == 0) { red[w] = s; red[w + 4] = s2; }
    __syncthreads();
    if (threadIdx.x == 0) {
        s  = red[0] + red[1] + red[2] + red[3];
        s2 = red[4] + red[5] + red[6] + red[7];
        float invn = 1.f / (float)(8 * S);
        float mean = s * invn;
        float var = s2 * invn - mean * mean;
        if (var < 0.f) var = 0.f;
        stats[bg * 2]     = mean;
        stats[bg * 2 + 1] = 1.f / sqrtf(var + 1e-5f);
    }
}

// GroupNorm stats from bf16 hi/lo pair (q path).
__global__ __launch_bounds__(256) void gn_stats_pair(
    const unsigned short* __restrict__ hi, const unsigned short* __restrict__ lo,
    float* __restrict__ stats, int S)
{
    int bg = blockIdx.x;
    const uint4* ph = (const uint4*)(hi + (size_t)bg * 8 * S);
    const uint4* pl = (const uint4*)(lo + (size_t)bg * 8 * S);
    int n8 = S;
    float s = 0.f, s2 = 0.f;
    for (int i = threadIdx.x; i < n8; i += 256) {
        uint4 a = ph[i], b2 = pl[i];
        unsigned ua[4] = {a.x, a.y, a.z, a.w}, ub[4] = {b2.x, b2.y, b2.z, b2.w};
        #pragma unroll
        for (int j = 0; j < 4; ++j) {
            float x0 = __uint_as_float(ua[j] << 16) + __uint_as_float(ub[j] << 16);
            float x1 = __uint_as_float(ua[j] & 0xffff0000u) + __uint_as_float(ub[j] & 0xffff0000u);
            s += x0 + x1;
            s2 += x0 * x0 + x1 * x1;
        }
    }
    for (int d = 1; d < 64; d <<= 1) { s += __shfl_xor(s, d); s2 += __shfl_xor(s2, d); }
    __shared__ float red[8];
    int w = threadIdx.x >> 6;
    if ((threadIdx.x & 63) == 0) { red[w] = s; red[w + 4] = s2; }
    __syncthreads();
    if (threadIdx.x == 0) {
        s  = red[0] + red[1] + red[2] + red[3];
        s2 = red[4] + red[5] + red[6] + red[7];
        float invn = 1.f / (float)(8 * S);
        float mean = s * invn;
        float var = s2 * invn - mean * mean;
        if (var < 0.f) var = 0.f;
        stats[bg * 2]     = mean;
        stats[bg * 2 + 1] = 1.f / sqrtf(var + 1e-5f);
    }
}

// GN + affine + SiLU (+extra scale) on bf16 pair, in place (q path, N=4096).
__global__ __launch_bounds__(256) void gn_silu_pair(
    unsigned short* __restrict__ hi, unsigned short* __restrict__ lo,
    const float* __restrict__ stats, const float* __restrict__ scale,
    const float* __restrict__ bias, float extra, int total8)
{
    int idx = blockIdx.x * 256 + threadIdx.x;
    if (idx >= total8) return;
    size_t e = (size_t)idx * 8;
    int c  = (int)((e >> 12) & 255);
    int gg = (int)(e >> 15);
    float mean = stats[gg * 2], rstd = stats[gg * 2 + 1];
    float a  = scale[c] * rstd;
    float bb = bias[c] - mean * a;
    uint4 uh = ((uint4*)hi)[idx], ul = ((uint4*)lo)[idx];
    unsigned ha[4] = {uh.x, uh.y, uh.z, uh.w}, la[4] = {ul.x, ul.y, ul.z, ul.w};
    unsigned oh[4], ol[4];
    #pragma unroll
    for (int j = 0; j < 4; ++j) {
        float x0 = __uint_as_float(ha[j] << 16) + __uint_as_float(la[j] << 16);
        float x1 = __uint_as_float(ha[j] & 0xffff0000u) + __uint_as_float(la[j] & 0xffff0000u);
        float y0 = x0 * a + bb, y1 = x1 * a + bb;
        float s0 = extra * y0 / (1.f + __expf(-y0));
        float s1 = extra * y1 / (1.f + __expf(-y1));
        unsigned short h0 = f2bf(s0), l0 = f2bf(s0 - bf2f(h0));
        unsigned short h1 = f2bf(s1), l1 = f2bf(s1 - bf2f(h1));
        oh[j] = h0 | ((unsigned)h1 << 16);
        ol[j] = l0 | ((unsigned)l1 << 16);
    }
    ((uint4*)hi)[idx] = make_uint4(oh[0], oh[1], oh[2], oh[3]);
    ((uint4*)lo)[idx] = make_uint4(ol[0], ol[1], ol[2], ol[3]);
}

// GN + affine + SiLU on fp32 v -> bf16 hi/lo pair, natural [C][M] layout.
__global__ __launch_bounds__(256) void gn_silu_split_v(
    const float* __restrict__ vf, unsigned short* __restrict__ hi,
    unsigned short* __restrict__ lo, const float* __restrict__ stats,
    const float* __restrict__ scale, const float* __restrict__ bias, int total8)
{
    int idx = blockIdx.x * 256 + threadIdx.x;
    if (idx >= total8) return;
    size_t e = (size_t)idx * 8;
    int c  = (int)((e >> 10) & 255);
    int gg = (int)(e >> 13);
    float mean = stats[gg * 2], rstd = stats[gg * 2 + 1];
    float a  = scale[c] * rstd;
    float bb = bias[c] - mean * a;
    float4 f0 = ((const float4*)vf)[idx * 2];
    float4 f1 = ((const float4*)vf)[idx * 2 + 1];
    float xs[8] = {f0.x, f0.y, f0.z, f0.w, f1.x, f1.y, f1.z, f1.w};
    unsigned oh[4], ol[4];
    #pragma unroll
    for (int j = 0; j < 4; ++j) {
        float y0 = xs[2 * j] * a + bb, y1 = xs[2 * j + 1] * a + bb;
        float s0 = y0 / (1.f + __expf(-y0));
        float s1 = y1 / (1.f + __expf(-y1));
        unsigned short h0 = f2bf(s0), l0 = f2bf(s0 - bf2f(h0));
        unsigned short h1 = f2bf(s1), l1 = f2bf(s1 - bf2f(h1));
        oh[j] = h0 | ((unsigned)h1 << 16);
        ol[j] = l0 | ((unsigned)l1 << 16);
    }
    ((uint4*)hi)[idx] = make_uint4(oh[0], oh[1], oh[2], oh[3]);
    ((uint4*)lo)[idx] = make_uint4(ol[0], ol[1], ol[2], ol[3]);
}

// GN + affine + SiLU on fp32 k -> TRANSPOSED bf16 hi/lo [B][M][C] (B-frag layout).
__global__ __launch_bounds__(256) void gn_silu_split_kT(
    const float* __restrict__ kf, unsigned short* __restrict__ th,
    unsigned short* __restrict__ tl, const float* __restrict__ stats,
    const float* __restrict__ scale, const float* __restrict__ bias)
{
    int bm = blockIdx.x;              // 8 batches * 128 m8-groups
    int b = bm >> 7, m8 = (bm & 127) * 8;
    int c = threadIdx.x;
    int gg = b * 32 + (c >> 3);
    float mean = stats[gg * 2], rstd = stats[gg * 2 + 1];
    float a  = scale[c] * rstd;
    float bb = bias[c] - mean * a;
    const float* src = kf + (((size_t)(b * 256 + c)) << 10) + m8;
    float4 f0 = *(const float4*)src;
    float4 f1 = *(const float4*)(src + 4);
    float xs[8] = {f0.x, f0.y, f0.z, f0.w, f1.x, f1.y, f1.z, f1.w};
    #pragma unroll
    for (int j = 0; j < 8; ++j) {
        float y = xs[j] * a + bb;
        float s = y / (1.f + __expf(-y));
        unsigned short h = f2bf(s), l = f2bf(s - bf2f(h));
        size_t o = ((size_t)b * M_ + m8 + j) * C_ + c;
        th[o] = h;
        tl[o] = l;
    }
}

// ---------------------------------------------------------------------------
// Fused flash attention, split-bf16 MFMA (3-term fp32 emulation).
__global__ __launch_bounds__(256, 2) void attn_mfma(
    const unsigned short* __restrict__ qh, const unsigned short* __restrict__ qlo,
    const unsigned short* __restrict__ kth, const unsigned short* __restrict__ ktl,
    const unsigned short* __restrict__ vh, const unsigned short* __restrict__ vlo,
    const float* __restrict__ gamma, float* __restrict__ out)
{
    __shared__ __align__(16) unsigned short pH[4][16][40];
    __shared__ __align__(16) unsigned short pL[4][16][40];
    __shared__ float alphaS[4][16];
    __shared__ float linvS[4][16];

    int blk = blockIdx.x;
    int bat = blk & 7;
    int nt  = blk >> 3;
    int t = threadIdx.x;
    int w = t >> 6;
    int lane = t & 63;
    int ll = lane & 15;
    int qd = lane >> 4;
    int n0 = nt * 64 + w * 16;

    short8 aqh[8], aql[8];
    {
        const unsigned short* qb1 = qh  + (size_t)bat * C_ * N_ + n0 + ll;
        const unsigned short* qb2 = qlo + (size_t)bat * C_ * N_ + n0 + ll;
        #pragma unroll
        for (int ks = 0; ks < 8; ++ks) {
            #pragma unroll
            for (int j = 0; j < 8; ++j) {
                size_t off = (size_t)(ks * 32 + qd * 8 + j) * N_;
                aqh[ks][j] = (short)qb1[off];
                aql[ks][j] = (short)qb2[off];
            }
        }
    }

    f32x4 oacc[16];
    #pragma unroll
    for (int i = 0; i < 16; ++i) oacc[i] = (f32x4){0.f, 0.f, 0.f, 0.f};
    float mrun[4] = {-3e38f, -3e38f, -3e38f, -3e38f};
    float lrun[4] = {0.f, 0.f, 0.f, 0.f};

    const unsigned short* ktbh = kth + (size_t)bat * M_ * C_ + (size_t)ll * C_ + qd * 8;
    const unsigned short* ktbl = ktl + (size_t)bat * M_ * C_ + (size_t)ll * C_ + qd * 8;
    const unsigned short* vbh  = vh  + (size_t)bat * C_ * M_ + (size_t)ll * M_ + qd * 8;
    const unsigned short* vbl  = vlo + (size_t)bat * C_ * M_ + (size_t)ll * M_ + qd * 8;

    for (int mt = 0; mt < 32; ++mt) {
        int m0 = mt * 32;
        f32x4 s0 = {0.f, 0.f, 0.f, 0.f}, s1 = {0.f, 0.f, 0.f, 0.f};
        const unsigned short* k0h = ktbh + (size_t)m0 * C_;
        const unsigned short* k0l = ktbl + (size_t)m0 * C_;
        const unsigned short* k1h = k0h + 16 * C_;
        const unsigned short* k1l = k0l + 16 * C_;
        #pragma unroll
        for (int ks = 0; ks < 8; ++ks) {
            short8 b0h = *(const short8*)(k0h + ks * 32);
            short8 b0l = *(const short8*)(k0l + ks * 32);
            short8 b1h = *(const short8*)(k1h + ks * 32);
            short8 b1l = *(const short8*)(k1l + ks * 32);
            s0 = __builtin_amdgcn_mfma_f32_16x16x32_bf16(aqh[ks], b0h, s0, 0, 0, 0);
            s1 = __builtin_amdgcn_mfma_f32_16x16x32_bf16(aqh[ks], b1h, s1, 0, 0, 0);
            s0 = __builtin_amdgcn_mfma_f32_16x16x32_bf16(aql[ks], b0h, s0, 0, 0, 0);
            s1 = __builtin_amdgcn_mfma_f32_16x16x32_bf16(aql[ks], b1h, s1, 0, 0, 0);
            s0 = __builtin_amdgcn_mfma_f32_16x16x32_bf16(aqh[ks], b0l, s0, 0, 0, 0);
            s1 = __builtin_amdgcn_mfma_f32_16x16x32_bf16(aqh[ks], b1l, s1, 0, 0, 0);
        }
        float alpha4[4];
        #pragma unroll
        for (int r = 0; r < 4; ++r) {
            float mx = fmaxf(s0[r], s1[r]);
            mx = fmaxf(mx, __shfl_xor(mx, 1));
            mx = fmaxf(mx, __shfl_xor(mx, 2));
            mx = fmaxf(mx, __shfl_xor(mx, 4));
            mx = fmaxf(mx, __shfl_xor(mx, 8));
            float mn = fmaxf(mrun[r], mx);
            float al = __expf(mrun[r] - mn);
            mrun[r] = mn;
            float p0 = __expf(s0[r] - mn);
            float p1 = __expf(s1[r] - mn);
            float ps = p0 + p1;
            ps += __shfl_xor(ps, 1);
            ps += __shfl_xor(ps, 2);
            ps += __shfl_xor(ps, 4);
            ps += __shfl_xor(ps, 8);
            lrun[r] = lrun[r] * al + ps;
            alpha4[r] = al;
            unsigned short h0 = f2bf(p0), l0 = f2bf(p0 - bf2f(h0));
            unsigned short h1 = f2bf(p1), l1 = f2bf(p1 - bf2f(h1));
            int rn = qd * 4 + r;
            pH[w][rn][ll] = h0;  pH[w][rn][16 + ll] = h1;
            pL[w][rn][ll] = l0;  pL[w][rn][16 + ll] = l1;
        }
        if (ll == 0) {
            #pragma unroll
            for (int r = 0; r < 4; ++r) alphaS[w][qd * 4 + r] = alpha4[r];
        }
        __builtin_amdgcn_wave_barrier();
        short8 bph = *(const short8*)&pH[w][ll][qd * 8];
        short8 bpl = *(const short8*)&pL[w][ll][qd * 8];
        float an = alphaS[w][ll];
        const unsigned short* vp0 = vbh + m0;
        const unsigned short* vp1 = vbl + m0;
        #pragma unroll
        for (int ct = 0; ct < 16; ++ct) {
            short8 avh = *(const short8*)(vp0 + (size_t)ct * 16 * M_);
            short8 avl = *(const short8*)(vp1 + (size_t)ct * 16 * M_);
            f32x4 o = oacc[ct];
            o[0] *= an; o[1] *= an; o[2] *= an; o[3] *= an;
            o = __builtin_amdgcn_mfma_f32_16x16x32_bf16(avh, bph, o, 0, 0, 0);
            o = __builtin_amdgcn_mfma_f32_16x16x32_bf16(avl, bph, o, 0, 0, 0);
            o = __builtin_amdgcn_mfma_f32_16x16x32_bf16(avh, bpl, o, 0, 0, 0);
            oacc[ct] = o;
        }
        __builtin_amdgcn_wave_barrier();
    }
    if (ll == 0) {
        #pragma unroll
        for (int r = 0; r < 4; ++r) linvS[w][qd * 4 + r] = 1.f / lrun[r];
    }
    __builtin_amdgcn_wave_barrier();
    float li = linvS[w][ll] * gamma[0];
    float* ob = out + (size_t)bat * C_ * N_ + n0 + ll;
    #pragma unroll
    for (int ct = 0; ct < 16; ++ct) {
        #pragma unroll
        for (int r = 0; r < 4; ++r) {
            int c = ct * 16 + qd * 4 + r;
            ob[(size_t)c * N_] = oacc[ct][r] * li;
        }
    }
}

// ---------------------------------------------------------------------------
extern "C" void kernel_launch(void* const* d_in, const int* in_sizes, int n_in,
                              void* d_out, int out_size, void* d_ws, size_t ws_size,
                              hipStream_t stream)
{
    const float* x   = (const float*)d_in[0];
    const float* y   = (const float*)d_in[1];
    const float* Wq  = (const float*)d_in[2];
    const float* bq  = (const float*)d_in[3];
    const float* gqs = (const float*)d_in[4];
    const float* gqb = (const float*)d_in[5];
    const float* Wk  = (const float*)d_in[6];
    const float* bk  = (const float*)d_in[7];
    const float* gks = (const float*)d_in[8];
    const float* gkb = (const float*)d_in[9];
    const float* Wv  = (const float*)d_in[10];
    const float* bv  = (const float*)d_in[11];
    const float* gvs = (const float*)d_in[12];
    const float* gvb = (const float*)d_in[13];
    const float* gamma = (const float*)d_in[14];
    float* out = (float*)d_out;

    // ws layout (~71.6 MB total):
    //   qH, qL: 2 x 16.78 MB
    //   regA (overlaid):
    //     conv3x3 phase: xpH,xpL [8][66][66][256] bf16 (35.68 MB) + wtH,wtL (2.36 MB)
    //     after:         kf,vf fp32 (16.78) + kTh,kTl,vH,vL (16.78) + stats
    char* base = (char*)d_ws;
    unsigned short* qH = (unsigned short*)base;
    unsigned short* qL = qH + 8388608;
    char* regA = (char*)(qL + 8388608);
    // overlay 1 (conv3x3 phase)
    unsigned short* xpH = (unsigned short*)regA;      // 8921088 shorts
    unsigned short* xpL = xpH + 8921088;
    unsigned short* wtH = xpL + 8921088;              // 589824 shorts
    unsigned short* wtL = wtH + 589824;
    // overlay 2 (rest of pipeline)
    float* kf = (float*)regA;
    float* vf = kf + 2097152;
    unsigned short* kTh = (unsigned short*)(vf + 2097152);
    unsigned short* kTl = kTh + 2097152;
    unsigned short* vH  = kTl + 2097152;
    unsigned short* vL  = vH + 2097152;
    float* stq = (float*)(vL + 2097152);
    float* stk = stq + 512;
    float* stv = stk + 512;

    // conv3x3 (q path) via MFMA
    hipMemsetAsync(xpH, 0, (size_t)2 * 8921088 * sizeof(unsigned short), stream);
    split_w_tap<<<256, 256, 0, stream>>>(Wq, wtH, wtL);
    split_x_pad<<<512, 256, 0, stream>>>(x, xpH, xpL);
    conv3x3_mfma<<<512, 256, 0, stream>>>(xpH, xpL, wtH, wtL, bq, qH, qL);

    // conv2x2 (k,v) — overwrites overlay region after conv3x3 completes (stream order)
    conv2x2_kernel<<<256, 256, 0, stream>>>(y, Wk, bk, Wv, bv, kf, vf);
    gn_stats_pair<<<256, 256, 0, stream>>>(qH, qL, stq, 4096);
    gn_stats_kernel<<<256, 256, 0, stream>>>(kf, stk, 1024);
    gn_stats_kernel<<<256, 256, 0, stream>>>(vf, stv, 1024);
    gn_silu_pair<<<4096, 256, 0, stream>>>(qH, qL, stq, gqs, gqb, 0.0625f, 1048576);
    gn_silu_split_v<<<1024, 256, 0, stream>>>(vf, vH, vL, stv, gvs, gvb, 262144);
    gn_silu_split_kT<<<1024, 256, 0, stream>>>(kf, kTh, kTl, stk, gks, gkb);
    attn_mfma<<<512, 256, 0, stream>>>(qH, qL, kTh, kTl, vH, vL, gamma, out);
}